// Round 9
// baseline (1066.512 us; speedup 1.0000x reference)
//
#include <hip/hip_runtime.h>
#include <hip/hip_bf16.h>
#include <math.h>

// EnvelopeWassersteinLoss: n=m=8192, d=64, EPS=0.05, 20 Sinkhorn iterations.
//   prep:     XP,XQ f32 -> bf16 + row sq-norms
//   gemm_max: MFMA GEMM -> per-block max -> bm[]
//   max_red:  bm[4096] -> reg, inv_reg
//   gemm_K:   GEMM again; K = exp(-C/reg); byte code L with BIT-LINEAR decode:
//               K~ = as_float(0x3F700000 - (L<<20))    (1 shift + 1 sub)
//             32-octave x 8-step piecewise-linear-log grid, K~ in [2^-32, 0.9375].
//             C~ = -reg*ln K~ is exact by construction (loss uses logf once).
//   sink:     block = 8 rows; codes loaded ONCE into 64 VGPRs, reused for both
//             phase A (x=Kv -> u=a/x) and phase B (y_part = K^T u, bf16)
//   reduce_v: v = b / sum_chunks y_part   (1024 bf16 chunks)
//   loss:     A_i = sum K~ v, B_i = sum ln(K~) K~ v -> tt_i = B_i/A_i
//   final:    out = (-reg/N) * sum_i tt_i

#define NN 8192
#define DD 64
#define EPSV 0.05f
#define NITER 20

typedef __attribute__((ext_vector_type(8))) short short8;            // 8 x bf16
typedef __attribute__((ext_vector_type(8))) unsigned short ushort8;  // 8 x bf16 bits
typedef __attribute__((ext_vector_type(4))) float fx4;

__device__ inline float bf2f(unsigned short u) {
    union { unsigned int i; float f; } x; x.i = ((unsigned int)u) << 16; return x.f;
}
__device__ inline unsigned short f2bf(float f) {
    union { float f; unsigned int i; } x; x.f = f;
    unsigned int r = x.i + 0x7fffu + ((x.i >> 16) & 1u);
    return (unsigned short)(r >> 16);
}
// 2-op decode: K~ = as_float(0x3F700000 - (L<<20))
__device__ inline float decK(unsigned int b) {
    return __uint_as_float(0x3F700000u - (b << 20));
}
__device__ inline void dec4_dot(unsigned int cw, fx4 v, float& acc) {
    acc += decK(cw & 255u) * v[0];
    acc += decK((cw >> 8) & 255u) * v[1];
    acc += decK((cw >> 16) & 255u) * v[2];
    acc += decK(cw >> 24) * v[3];
}
__device__ inline void dec4_axpy(unsigned int cw, float u, fx4& ya) {
    ya[0] += decK(cw & 255u) * u;
    ya[1] += decK((cw >> 8) & 255u) * u;
    ya[2] += decK((cw >> 16) & 255u) * u;
    ya[3] += decK(cw >> 24) * u;
}
__device__ inline void dec4_loss(unsigned int cw, fx4 v, float& accA, float& accB) {
    #pragma unroll
    for (int e = 0; e < 4; ++e) {
        float g = decK((cw >> (8 * e)) & 255u);
        float gv = g * v[e];
        accA += gv;
        accB += __logf(g) * gv;
    }
}

// ---------------- prep: convert + row norms ----------------
__global__ __launch_bounds__(256) void prep_k(const float* __restrict__ XP,
                                              const float* __restrict__ XQ,
                                              unsigned short* __restrict__ XPb,
                                              unsigned short* __restrict__ XQb,
                                              float* __restrict__ pn,
                                              float* __restrict__ qn) {
    int task = blockIdx.x * 4 + (threadIdx.x >> 6);
    int lane = threadIdx.x & 63;
    const float* src; unsigned short* dst; float* nrm; int row;
    if (task < NN) { src = XP; dst = XPb; nrm = pn; row = task; }
    else           { src = XQ; dst = XQb; nrm = qn; row = task - NN; }
    float xv = src[row * DD + lane];
    dst[row * DD + lane] = f2bf(xv);
    float s = xv * xv;
    #pragma unroll
    for (int o = 32; o; o >>= 1) s += __shfl_xor(s, o);
    if (lane == 0) nrm[row] = s;
}

// ---------------- shared GEMM tile: wave computes 64x64 via 4x4 MFMA frags ----------------
__device__ inline void gemm_tile(const unsigned short* __restrict__ XPb,
                                 const unsigned short* __restrict__ XQb,
                                 int R0, int C0, int lane, fx4 acc[4][4]) {
    int r  = lane & 15;
    int ko = (lane >> 4) * 8;
    #pragma unroll
    for (int kk = 0; kk < DD; kk += 32) {
        short8 a[4], b[4];
        #pragma unroll
        for (int m = 0; m < 4; m++)
            a[m] = *(const short8*)(XPb + (R0 + m * 16 + r) * DD + kk + ko);
        #pragma unroll
        for (int n = 0; n < 4; n++)
            b[n] = *(const short8*)(XQb + (C0 + n * 16 + r) * DD + kk + ko);
        #pragma unroll
        for (int m = 0; m < 4; m++)
            #pragma unroll
            for (int n = 0; n < 4; n++)
                acc[m][n] = __builtin_amdgcn_mfma_f32_16x16x32_bf16(a[m], b[n], acc[m][n], 0, 0, 0);
    }
}

// ---------------- pass 1: per-block max of C -> bm[] ----------------
__global__ __launch_bounds__(256) void gemm_max_k(const unsigned short* __restrict__ XPb,
                                                  const unsigned short* __restrict__ XQb,
                                                  const float* __restrict__ pn,
                                                  const float* __restrict__ qn,
                                                  float* __restrict__ bm) {
    int w = threadIdx.x >> 6, wr = w >> 1, wc = w & 1;
    int lane = threadIdx.x & 63;
    int R0 = blockIdx.y * 128 + wr * 64;
    int C0 = blockIdx.x * 128 + wc * 64;
    fx4 acc[4][4] = {};
    gemm_tile(XPb, XQb, R0, C0, lane, acc);

    float pl = pn[R0 + lane], ql = qn[C0 + lane];
    float pr[16], qc[4];
    #pragma unroll
    for (int m = 0; m < 4; m++)
        #pragma unroll
        for (int j = 0; j < 4; j++)
            pr[m * 4 + j] = __shfl(pl, m * 16 + ((lane >> 4) << 2) + j);
    #pragma unroll
    for (int n = 0; n < 4; n++) qc[n] = __shfl(ql, n * 16 + (lane & 15));

    float mx = 0.0f;
    #pragma unroll
    for (int m = 0; m < 4; m++)
        #pragma unroll
        for (int n = 0; n < 4; n++)
            #pragma unroll
            for (int j = 0; j < 4; j++)
                mx = fmaxf(mx, pr[m * 4 + j] + qc[n] - 2.0f * acc[m][n][j]);
    #pragma unroll
    for (int o = 32; o; o >>= 1) mx = fmaxf(mx, __shfl_xor(mx, o));
    __shared__ float wmax[4];
    if (lane == 0) wmax[w] = mx;
    __syncthreads();
    if (threadIdx.x == 0)
        bm[blockIdx.y * 64 + blockIdx.x] = fmaxf(fmaxf(wmax[0], wmax[1]), fmaxf(wmax[2], wmax[3]));
}

// ---------------- reduce bm[4096] -> regbuf {reg, inv_reg} ----------------
__global__ __launch_bounds__(256) void max_red_k(const float* __restrict__ bm,
                                                 float* __restrict__ regbuf) {
    int t = threadIdx.x;
    float mx = 0.0f;
    #pragma unroll
    for (int i = 0; i < 16; ++i) mx = fmaxf(mx, bm[i * 256 + t]);
    #pragma unroll
    for (int o = 32; o; o >>= 1) mx = fmaxf(mx, __shfl_xor(mx, o));
    __shared__ float wmax[4];
    if ((t & 63) == 0) wmax[t >> 6] = mx;
    __syncthreads();
    if (t == 0) {
        float m = fmaxf(fmaxf(wmax[0], wmax[1]), fmaxf(wmax[2], wmax[3]));
        float reg = EPSV * m;
        regbuf[0] = reg;
        regbuf[1] = 1.0f / reg;
    }
}

// ---------------- pass 2: byte code L (bit-linear decode), coalesced via LDS tile ----------------
__global__ __launch_bounds__(256) void gemm_K_k(const unsigned short* __restrict__ XPb,
                                                const unsigned short* __restrict__ XQb,
                                                const float* __restrict__ pn,
                                                const float* __restrict__ qn,
                                                const float* __restrict__ regbuf,
                                                unsigned char* __restrict__ Kb) {
    __shared__ unsigned char tile[128][136];
    int w = threadIdx.x >> 6, wr = w >> 1, wc = w & 1;
    int lane = threadIdx.x & 63;
    int R0 = blockIdx.y * 128 + wr * 64;
    int C0 = blockIdx.x * 128 + wc * 64;
    fx4 acc[4][4] = {};
    gemm_tile(XPb, XQb, R0, C0, lane, acc);

    float inv_reg = regbuf[1];
    float pl = pn[R0 + lane], ql = qn[C0 + lane];
    float pr[16], qc[4];
    #pragma unroll
    for (int m = 0; m < 4; m++)
        #pragma unroll
        for (int j = 0; j < 4; j++)
            pr[m * 4 + j] = __shfl(pl, m * 16 + ((lane >> 4) << 2) + j);
    #pragma unroll
    for (int n = 0; n < 4; n++) qc[n] = __shfl(ql, n * 16 + (lane & 15));

    #pragma unroll
    for (int m = 0; m < 4; m++) {
        #pragma unroll
        for (int n = 0; n < 4; n++) {
            #pragma unroll
            for (int j = 0; j < 4; j++) {
                float c = fmaxf(pr[m * 4 + j] + qc[n] - 2.0f * acc[m][n][j], 0.0f);
                float kv = __expf(-c * inv_reg);
                int L = (0x3F700000 - (int)__float_as_uint(kv) + 0x80000) >> 20;
                L = L < 0 ? 0 : (L > 255 ? 255 : L);
                int lr = wr * 64 + m * 16 + ((lane >> 4) << 2) + j;
                int lc = wc * 64 + n * 16 + (lane & 15);
                tile[lr][lc] = (unsigned char)L;
            }
        }
    }
    __syncthreads();

    int lane16 = threadIdx.x & 15;
    int rowgrp = threadIdx.x >> 4;
    size_t Rg = (size_t)blockIdx.y * 128;
    int Cg = blockIdx.x * 128;
    #pragma unroll
    for (int s = 0; s < 8; ++s) {
        int row = s * 16 + rowgrp;
        uint2 pk = *(const uint2*)&tile[row][lane16 * 8];
        *(uint2*)(Kb + (Rg + row) * NN + Cg + lane16 * 8) = pk;
    }
}

// ---------------- fused Sinkhorn pass: 8 rows/block, codes held in VGPRs across phases ----------------
// phase A (iter>0): x_i = sum_j K~_ij v_j  -> u_i = (1/N)/x_i
// phase B:          y_part[blk][j] = sum_{i in blk} u_i K~_ij   (bf16)
__global__ __launch_bounds__(256) void sink_k(const unsigned char* __restrict__ Kb,
                                              const float* __restrict__ vv,
                                              unsigned short* __restrict__ y_part,
                                              int iter) {
    __shared__ float xr[4][8];
    __shared__ float us[8];

    int t = threadIdx.x;
    int w = t >> 6, l = t & 63;
    size_t r0 = (size_t)blockIdx.x * 8;
    int cbase = w * 2048 + l * 16;
    const unsigned char* base = Kb + r0 * NN + cbase;

    // load ALL codes once: 8 rows x 32B/thread = 16 x uint4 = 64 VGPRs
    uint4 cb[16];
    #pragma unroll
    for (int i = 0; i < 8; ++i) {
        cb[2 * i]     = *(const uint4*)(base + (size_t)i * NN);
        cb[2 * i + 1] = *(const uint4*)(base + (size_t)i * NN + 1024);
    }

    if (iter != 0) {
        fx4 vr[8];
        #pragma unroll
        for (int it = 0; it < 2; ++it)
            #pragma unroll
            for (int q = 0; q < 4; ++q)
                vr[it * 4 + q] = *(const fx4*)(vv + cbase + it * 1024 + q * 4);

        #pragma unroll
        for (int i = 0; i < 8; ++i) {
            float a0 = 0, a1 = 0, a2 = 0, a3 = 0;   // 4 independent chains
            dec4_dot(cb[2 * i].x, vr[0], a0);
            dec4_dot(cb[2 * i].y, vr[1], a1);
            dec4_dot(cb[2 * i].z, vr[2], a2);
            dec4_dot(cb[2 * i].w, vr[3], a3);
            dec4_dot(cb[2 * i + 1].x, vr[4], a0);
            dec4_dot(cb[2 * i + 1].y, vr[5], a1);
            dec4_dot(cb[2 * i + 1].z, vr[6], a2);
            dec4_dot(cb[2 * i + 1].w, vr[7], a3);
            float acc = (a0 + a1) + (a2 + a3);
            #pragma unroll
            for (int o = 32; o; o >>= 1) acc += __shfl_xor(acc, o);
            if (l == 0) xr[w][i] = acc;
        }
        __syncthreads();
        if (t < 8) us[t] = (1.0f / (float)NN) / (xr[0][t] + xr[1][t] + xr[2][t] + xr[3][t]);
        __syncthreads();
    } else {
        if (t < 8) us[t] = 1.0f / (float)NN;
        __syncthreads();
    }

    // phase B straight from registers — no second memory read of K
    fx4 ya[8] = {};
    #pragma unroll
    for (int i = 0; i < 8; ++i) {
        float u = us[i];
        dec4_axpy(cb[2 * i].x, u, ya[0]);
        dec4_axpy(cb[2 * i].y, u, ya[1]);
        dec4_axpy(cb[2 * i].z, u, ya[2]);
        dec4_axpy(cb[2 * i].w, u, ya[3]);
        dec4_axpy(cb[2 * i + 1].x, u, ya[4]);
        dec4_axpy(cb[2 * i + 1].y, u, ya[5]);
        dec4_axpy(cb[2 * i + 1].z, u, ya[6]);
        dec4_axpy(cb[2 * i + 1].w, u, ya[7]);
    }
    #pragma unroll
    for (int it = 0; it < 2; ++it) {
        ushort8 o0, o1;
        #pragma unroll
        for (int e = 0; e < 4; ++e) {
            o0[e]     = f2bf(ya[it * 4 + 0][e]);
            o0[e + 4] = f2bf(ya[it * 4 + 1][e]);
            o1[e]     = f2bf(ya[it * 4 + 2][e]);
            o1[e + 4] = f2bf(ya[it * 4 + 3][e]);
        }
        unsigned short* yp = y_part + (size_t)blockIdx.x * NN + cbase + it * 1024;
        *(ushort8*)yp = o0;
        *(ushort8*)(yp + 8) = o1;
    }
}

// ---------------- v[j] = b / sum_c y_part[c][j]  (1024 bf16 chunks) ----------------
__global__ __launch_bounds__(256) void reduce_v_k(const unsigned short* __restrict__ y_part,
                                                  float* __restrict__ vv) {
    int t = threadIdx.x;
    int w = t >> 6, l = t & 63;
    int col = blockIdx.x * 64 + l;
    float s = 0.0f;
    #pragma unroll 8
    for (int c = w * 256; c < w * 256 + 256; ++c)
        s += bf2f(y_part[(size_t)c * NN + col]);
    __shared__ float part[4][64];
    part[w][l] = s;
    __syncthreads();
    if (t < 64) {
        float y = part[0][t] + part[1][t] + part[2][t] + part[3][t];
        vv[blockIdx.x * 64 + t] = (1.0f / (float)NN) / y;
    }
}

// ---------------- loss pass: A_i = sum K~ v, B_i = sum ln(K~) K~ v -> tt = B/A ----------------
__global__ __launch_bounds__(256) void loss_k(const unsigned char* __restrict__ Kb,
                                              const float* __restrict__ vv,
                                              float* __restrict__ tt) {
    __shared__ float xrA[4][16];
    __shared__ float xrB[4][16];
    int t = threadIdx.x;
    int w = t >> 6, l = t & 63;
    size_t r0 = (size_t)blockIdx.x * 16;
    int cbase = w * 2048 + l * 16;
    fx4 vr[8];
    #pragma unroll
    for (int it = 0; it < 2; ++it)
        #pragma unroll
        for (int q = 0; q < 4; ++q)
            vr[it * 4 + q] = *(const fx4*)(vv + cbase + it * 1024 + q * 4);

    #pragma unroll
    for (int i = 0; i < 16; ++i) {
        float accA = 0.0f, accB = 0.0f;
        uint4 cbA = *(const uint4*)(Kb + (r0 + i) * NN + cbase);
        uint4 cbB = *(const uint4*)(Kb + (r0 + i) * NN + cbase + 1024);
        dec4_loss(cbA.x, vr[0], accA, accB);
        dec4_loss(cbA.y, vr[1], accA, accB);
        dec4_loss(cbA.z, vr[2], accA, accB);
        dec4_loss(cbA.w, vr[3], accA, accB);
        dec4_loss(cbB.x, vr[4], accA, accB);
        dec4_loss(cbB.y, vr[5], accA, accB);
        dec4_loss(cbB.z, vr[6], accA, accB);
        dec4_loss(cbB.w, vr[7], accA, accB);
        #pragma unroll
        for (int o = 32; o; o >>= 1) {
            accA += __shfl_xor(accA, o);
            accB += __shfl_xor(accB, o);
        }
        if (l == 0) { xrA[w][i] = accA; xrB[w][i] = accB; }
    }
    __syncthreads();
    if (t < 16) {
        float A = xrA[0][t] + xrA[1][t] + xrA[2][t] + xrA[3][t];
        float B = xrB[0][t] + xrB[1][t] + xrB[2][t] + xrB[3][t];
        tt[r0 + t] = B / A;
    }
}

// ---------------- out = (-reg/N) * sum_i tt_i ----------------
__global__ __launch_bounds__(256) void final_loss_k(const float* __restrict__ tt,
                                                    const float* __restrict__ regbuf,
                                                    float* __restrict__ out) {
    int t = threadIdx.x;
    float s = 0.0f;
    for (int i = t; i < NN; i += 256)
        s += tt[i];
    #pragma unroll
    for (int o = 32; o; o >>= 1) s += __shfl_xor(s, o);
    __shared__ float wsum[4];
    if ((t & 63) == 0) wsum[t >> 6] = s;
    __syncthreads();
    if (t == 0)
        out[0] = -regbuf[0] * (wsum[0] + wsum[1] + wsum[2] + wsum[3]) / (float)NN;
}

extern "C" void kernel_launch(void* const* d_in, const int* in_sizes, int n_in,
                              void* d_out, int out_size, void* d_ws, size_t ws_size,
                              hipStream_t stream) {
    const float* XP = (const float*)d_in[0];
    const float* XQ = (const float*)d_in[1];
    float* out = (float*)d_out;

    // workspace layout (~82.5 MiB)
    char* p = (char*)d_ws;
    unsigned char* Kb = (unsigned char*)p;     p += (size_t)NN * NN;          // 64 MiB
    unsigned short* y_part = (unsigned short*)p; p += (size_t)1024 * NN * 2;  // 16 MiB
    unsigned short* XPb = (unsigned short*)p;  p += (size_t)NN * DD * 2;      // 1 MiB
    unsigned short* XQb = (unsigned short*)p;  p += (size_t)NN * DD * 2;      // 1 MiB
    float* pn = (float*)p;                     p += NN * 4;
    float* qn = (float*)p;                     p += NN * 4;
    float* vv = (float*)p;                     p += NN * 4;
    float* tt = (float*)p;                     p += NN * 4;
    float* bm = (float*)p;                     p += 4096 * 4;
    float* regbuf = (float*)p;

    prep_k<<<4096, 256, 0, stream>>>(XP, XQ, XPb, XQb, pn, qn);
    gemm_max_k<<<dim3(64, 64), 256, 0, stream>>>(XPb, XQb, pn, qn, bm);
    max_red_k<<<1, 256, 0, stream>>>(bm, regbuf);
    gemm_K_k<<<dim3(64, 64), 256, 0, stream>>>(XPb, XQb, pn, qn, regbuf, Kb);

    for (int it = 0; it < NITER; ++it) {
        sink_k<<<1024, 256, 0, stream>>>(Kb, vv, y_part, it);
        reduce_v_k<<<128, 256, 0, stream>>>(y_part, vv);
    }
    loss_k<<<512, 256, 0, stream>>>(Kb, vv, tt);
    final_loss_k<<<1, 256, 0, stream>>>(tt, regbuf, out);
}

// Round 11
// 843.618 us; speedup vs baseline: 1.2642x; 1.2642x over previous
//
#include <hip/hip_runtime.h>
#include <hip/hip_bf16.h>
#include <hip/hip_cooperative_groups.h>
#include <math.h>

namespace cg = cooperative_groups;

// EnvelopeWassersteinLoss: n=m=8192, d=64, EPS=0.05, 20 Sinkhorn iterations.
//   prep:     XP,XQ f32 -> bf16 + row sq-norms
//   gemm_max: MFMA GEMM -> per-block max -> bm[]
//   max_red:  bm[4096] -> reg, inv_reg
//   gemm_K:   GEMM again; K = exp(-C/reg); byte code L, BIT-LINEAR decode:
//               K~ = as_float(0x3F700000 - (L<<20))   (1 shift + 1 sub)
//   loop:     PREFERRED: one cooperative kernel, codes in VGPRs for all 20 iters
//             (occupancy-prechecked; launch return checked).
//             FALLBACK (deterministic, env-dependent only): round-8 proven loop
//             sink_k + reduce_v_k per iteration.
//   loss:     A_i = sum K~ v, B_i = sum ln(K~) K~ v -> tt_i = B_i/A_i
//   final:    out = (-reg/N) * sum_i tt_i

#define NN 8192
#define DD 64
#define EPSV 0.05f
#define NITER 20

typedef __attribute__((ext_vector_type(8))) short short8;            // 8 x bf16
typedef __attribute__((ext_vector_type(8))) unsigned short ushort8;  // 8 x bf16 bits
typedef __attribute__((ext_vector_type(4))) float fx4;

__device__ inline float bf2f(unsigned short u) {
    union { unsigned int i; float f; } x; x.i = ((unsigned int)u) << 16; return x.f;
}
__device__ inline unsigned short f2bf(float f) {
    union { float f; unsigned int i; } x; x.f = f;
    unsigned int r = x.i + 0x7fffu + ((x.i >> 16) & 1u);
    return (unsigned short)(r >> 16);
}
// 2-op decode: K~ = as_float(0x3F700000 - (L<<20))
__device__ inline float decK(unsigned int b) {
    return __uint_as_float(0x3F700000u - (b << 20));
}
__device__ inline void dec4_dot(unsigned int cw, fx4 v, float& acc) {
    acc += decK(cw & 255u) * v[0];
    acc += decK((cw >> 8) & 255u) * v[1];
    acc += decK((cw >> 16) & 255u) * v[2];
    acc += decK(cw >> 24) * v[3];
}
__device__ inline void dec4_axpy(unsigned int cw, float u, fx4& ya) {
    ya[0] += decK(cw & 255u) * u;
    ya[1] += decK((cw >> 8) & 255u) * u;
    ya[2] += decK((cw >> 16) & 255u) * u;
    ya[3] += decK(cw >> 24) * u;
}
__device__ inline void dec4_loss(unsigned int cw, fx4 v, float& accA, float& accB) {
    #pragma unroll
    for (int e = 0; e < 4; ++e) {
        float g = decK((cw >> (8 * e)) & 255u);
        float gv = g * v[e];
        accA += gv;
        accB += __logf(g) * gv;
    }
}

// ---------------- prep: convert + row norms ----------------
__global__ __launch_bounds__(256) void prep_k(const float* __restrict__ XP,
                                              const float* __restrict__ XQ,
                                              unsigned short* __restrict__ XPb,
                                              unsigned short* __restrict__ XQb,
                                              float* __restrict__ pn,
                                              float* __restrict__ qn) {
    int task = blockIdx.x * 4 + (threadIdx.x >> 6);
    int lane = threadIdx.x & 63;
    const float* src; unsigned short* dst; float* nrm; int row;
    if (task < NN) { src = XP; dst = XPb; nrm = pn; row = task; }
    else           { src = XQ; dst = XQb; nrm = qn; row = task - NN; }
    float xv = src[row * DD + lane];
    dst[row * DD + lane] = f2bf(xv);
    float s = xv * xv;
    #pragma unroll
    for (int o = 32; o; o >>= 1) s += __shfl_xor(s, o);
    if (lane == 0) nrm[row] = s;
}

// ---------------- shared GEMM tile: wave computes 64x64 via 4x4 MFMA frags ----------------
__device__ inline void gemm_tile(const unsigned short* __restrict__ XPb,
                                 const unsigned short* __restrict__ XQb,
                                 int R0, int C0, int lane, fx4 acc[4][4]) {
    int r  = lane & 15;
    int ko = (lane >> 4) * 8;
    #pragma unroll
    for (int kk = 0; kk < DD; kk += 32) {
        short8 a[4], b[4];
        #pragma unroll
        for (int m = 0; m < 4; m++)
            a[m] = *(const short8*)(XPb + (R0 + m * 16 + r) * DD + kk + ko);
        #pragma unroll
        for (int n = 0; n < 4; n++)
            b[n] = *(const short8*)(XQb + (C0 + n * 16 + r) * DD + kk + ko);
        #pragma unroll
        for (int m = 0; m < 4; m++)
            #pragma unroll
            for (int n = 0; n < 4; n++)
                acc[m][n] = __builtin_amdgcn_mfma_f32_16x16x32_bf16(a[m], b[n], acc[m][n], 0, 0, 0);
    }
}

// ---------------- pass 1: per-block max of C -> bm[] ----------------
__global__ __launch_bounds__(256) void gemm_max_k(const unsigned short* __restrict__ XPb,
                                                  const unsigned short* __restrict__ XQb,
                                                  const float* __restrict__ pn,
                                                  const float* __restrict__ qn,
                                                  float* __restrict__ bm) {
    int w = threadIdx.x >> 6, wr = w >> 1, wc = w & 1;
    int lane = threadIdx.x & 63;
    int R0 = blockIdx.y * 128 + wr * 64;
    int C0 = blockIdx.x * 128 + wc * 64;
    fx4 acc[4][4] = {};
    gemm_tile(XPb, XQb, R0, C0, lane, acc);

    float pl = pn[R0 + lane], ql = qn[C0 + lane];
    float pr[16], qc[4];
    #pragma unroll
    for (int m = 0; m < 4; m++)
        #pragma unroll
        for (int j = 0; j < 4; j++)
            pr[m * 4 + j] = __shfl(pl, m * 16 + ((lane >> 4) << 2) + j);
    #pragma unroll
    for (int n = 0; n < 4; n++) qc[n] = __shfl(ql, n * 16 + (lane & 15));

    float mx = 0.0f;
    #pragma unroll
    for (int m = 0; m < 4; m++)
        #pragma unroll
        for (int n = 0; n < 4; n++)
            #pragma unroll
            for (int j = 0; j < 4; j++)
                mx = fmaxf(mx, pr[m * 4 + j] + qc[n] - 2.0f * acc[m][n][j]);
    #pragma unroll
    for (int o = 32; o; o >>= 1) mx = fmaxf(mx, __shfl_xor(mx, o));
    __shared__ float wmax[4];
    if (lane == 0) wmax[w] = mx;
    __syncthreads();
    if (threadIdx.x == 0)
        bm[blockIdx.y * 64 + blockIdx.x] = fmaxf(fmaxf(wmax[0], wmax[1]), fmaxf(wmax[2], wmax[3]));
}

// ---------------- reduce bm[4096] -> regbuf {reg, inv_reg} ----------------
__global__ __launch_bounds__(256) void max_red_k(const float* __restrict__ bm,
                                                 float* __restrict__ regbuf) {
    int t = threadIdx.x;
    float mx = 0.0f;
    #pragma unroll
    for (int i = 0; i < 16; ++i) mx = fmaxf(mx, bm[i * 256 + t]);
    #pragma unroll
    for (int o = 32; o; o >>= 1) mx = fmaxf(mx, __shfl_xor(mx, o));
    __shared__ float wmax[4];
    if ((t & 63) == 0) wmax[t >> 6] = mx;
    __syncthreads();
    if (t == 0) {
        float m = fmaxf(fmaxf(wmax[0], wmax[1]), fmaxf(wmax[2], wmax[3]));
        float reg = EPSV * m;
        regbuf[0] = reg;
        regbuf[1] = 1.0f / reg;
    }
}

// ---------------- pass 2: byte code L (bit-linear decode), coalesced via LDS tile ----------------
__global__ __launch_bounds__(256) void gemm_K_k(const unsigned short* __restrict__ XPb,
                                                const unsigned short* __restrict__ XQb,
                                                const float* __restrict__ pn,
                                                const float* __restrict__ qn,
                                                const float* __restrict__ regbuf,
                                                unsigned char* __restrict__ Kb) {
    __shared__ unsigned char tile[128][136];
    int w = threadIdx.x >> 6, wr = w >> 1, wc = w & 1;
    int lane = threadIdx.x & 63;
    int R0 = blockIdx.y * 128 + wr * 64;
    int C0 = blockIdx.x * 128 + wc * 64;
    fx4 acc[4][4] = {};
    gemm_tile(XPb, XQb, R0, C0, lane, acc);

    float inv_reg = regbuf[1];
    float pl = pn[R0 + lane], ql = qn[C0 + lane];
    float pr[16], qc[4];
    #pragma unroll
    for (int m = 0; m < 4; m++)
        #pragma unroll
        for (int j = 0; j < 4; j++)
            pr[m * 4 + j] = __shfl(pl, m * 16 + ((lane >> 4) << 2) + j);
    #pragma unroll
    for (int n = 0; n < 4; n++) qc[n] = __shfl(ql, n * 16 + (lane & 15));

    #pragma unroll
    for (int m = 0; m < 4; m++) {
        #pragma unroll
        for (int n = 0; n < 4; n++) {
            #pragma unroll
            for (int j = 0; j < 4; j++) {
                float c = fmaxf(pr[m * 4 + j] + qc[n] - 2.0f * acc[m][n][j], 0.0f);
                float kv = __expf(-c * inv_reg);
                int L = (0x3F700000 - (int)__float_as_uint(kv) + 0x80000) >> 20;
                L = L < 0 ? 0 : (L > 255 ? 255 : L);
                int lr = wr * 64 + m * 16 + ((lane >> 4) << 2) + j;
                int lc = wc * 64 + n * 16 + (lane & 15);
                tile[lr][lc] = (unsigned char)L;
            }
        }
    }
    __syncthreads();

    int lane16 = threadIdx.x & 15;
    int rowgrp = threadIdx.x >> 4;
    size_t Rg = (size_t)blockIdx.y * 128;
    int Cg = blockIdx.x * 128;
    #pragma unroll
    for (int s = 0; s < 8; ++s) {
        int row = s * 16 + rowgrp;
        uint2 pk = *(const uint2*)&tile[row][lane16 * 8];
        *(uint2*)(Kb + (Rg + row) * NN + Cg + lane16 * 8) = pk;
    }
}

// ---------------- FALLBACK: round-8 proven per-iteration kernels ----------------
__global__ __launch_bounds__(256) void sink_k(const unsigned char* __restrict__ Kb,
                                              const float* __restrict__ vv,
                                              unsigned short* __restrict__ y_part,
                                              int iter) {
    __shared__ float xr[4][8];
    __shared__ float us[8];

    int t = threadIdx.x;
    int w = t >> 6, l = t & 63;
    size_t r0 = (size_t)blockIdx.x * 8;
    int cbase = w * 2048 + l * 16;
    const unsigned char* base = Kb + r0 * NN + cbase;

    if (iter != 0) {
        fx4 vr[8];
        #pragma unroll
        for (int it = 0; it < 2; ++it)
            #pragma unroll
            for (int q = 0; q < 4; ++q)
                vr[it * 4 + q] = *(const fx4*)(vv + cbase + it * 1024 + q * 4);

        #pragma unroll
        for (int i = 0; i < 8; ++i) {
            uint4 cbA = *(const uint4*)(base + (size_t)i * NN);
            uint4 cbB = *(const uint4*)(base + (size_t)i * NN + 1024);
            float a0 = 0, a1 = 0, a2 = 0, a3 = 0;
            dec4_dot(cbA.x, vr[0], a0);
            dec4_dot(cbA.y, vr[1], a1);
            dec4_dot(cbA.z, vr[2], a2);
            dec4_dot(cbA.w, vr[3], a3);
            dec4_dot(cbB.x, vr[4], a0);
            dec4_dot(cbB.y, vr[5], a1);
            dec4_dot(cbB.z, vr[6], a2);
            dec4_dot(cbB.w, vr[7], a3);
            float acc = (a0 + a1) + (a2 + a3);
            #pragma unroll
            for (int o = 32; o; o >>= 1) acc += __shfl_xor(acc, o);
            if (l == 0) xr[w][i] = acc;
        }
        __syncthreads();
        if (t < 8) us[t] = (1.0f / (float)NN) / (xr[0][t] + xr[1][t] + xr[2][t] + xr[3][t]);
        __syncthreads();
    } else {
        if (t < 8) us[t] = 1.0f / (float)NN;
        __syncthreads();
    }

    fx4 ya[8] = {};
    #pragma unroll
    for (int i = 0; i < 8; ++i) {
        float u = us[i];
        uint4 cbA = *(const uint4*)(base + (size_t)i * NN);
        uint4 cbB = *(const uint4*)(base + (size_t)i * NN + 1024);
        dec4_axpy(cbA.x, u, ya[0]);
        dec4_axpy(cbA.y, u, ya[1]);
        dec4_axpy(cbA.z, u, ya[2]);
        dec4_axpy(cbA.w, u, ya[3]);
        dec4_axpy(cbB.x, u, ya[4]);
        dec4_axpy(cbB.y, u, ya[5]);
        dec4_axpy(cbB.z, u, ya[6]);
        dec4_axpy(cbB.w, u, ya[7]);
    }
    #pragma unroll
    for (int it = 0; it < 2; ++it) {
        ushort8 o0, o1;
        #pragma unroll
        for (int e = 0; e < 4; ++e) {
            o0[e]     = f2bf(ya[it * 4 + 0][e]);
            o0[e + 4] = f2bf(ya[it * 4 + 1][e]);
            o1[e]     = f2bf(ya[it * 4 + 2][e]);
            o1[e + 4] = f2bf(ya[it * 4 + 3][e]);
        }
        unsigned short* yp = y_part + (size_t)blockIdx.x * NN + cbase + it * 1024;
        *(ushort8*)yp = o0;
        *(ushort8*)(yp + 8) = o1;
    }
}

__global__ __launch_bounds__(256) void reduce_v_k(const unsigned short* __restrict__ y_part,
                                                  float* __restrict__ vv) {
    int t = threadIdx.x;
    int w = t >> 6, l = t & 63;
    int col = blockIdx.x * 64 + l;
    float s = 0.0f;
    #pragma unroll 8
    for (int c = w * 256; c < w * 256 + 256; ++c)
        s += bf2f(y_part[(size_t)c * NN + col]);
    __shared__ float part[4][64];
    part[w][l] = s;
    __syncthreads();
    if (t < 64) {
        float y = part[0][t] + part[1][t] + part[2][t] + part[3][t];
        vv[blockIdx.x * 64 + t] = (1.0f / (float)NN) / y;
    }
}

// ---------------- PREFERRED: cooperative persistent Sinkhorn loop ----------------
// block = 8 rows; thread slab = 16 x uint4 codes held in VGPRs for all 20 iters.
__global__ __launch_bounds__(256, 4) void sink_coop_k(const unsigned char* __restrict__ Kb,
                                                      float* __restrict__ vv,
                                                      unsigned short* __restrict__ y_part) {
    cg::grid_group grid = cg::this_grid();
    __shared__ float xr[4][8];
    __shared__ float us_sh[8];
    __shared__ float red[8][33];

    int t = threadIdx.x;
    int w = t >> 6, l = t & 63;
    int blk = blockIdx.x;
    size_t r0 = (size_t)blk * 8;
    int cbase = w * 2048 + l * 16;
    const unsigned char* base = Kb + r0 * NN + cbase;

    // load codes ONCE for all 20 iterations: 8 rows x 32 cols = 16 x uint4
    uint4 cb[16];
    #pragma unroll
    for (int i = 0; i < 8; ++i) {
        cb[2 * i]     = *(const uint4*)(base + (size_t)i * NN);
        cb[2 * i + 1] = *(const uint4*)(base + (size_t)i * NN + 1024);
    }

    float us[8];

    for (int it = 0; it < NITER; ++it) {
        if (it == 0) {
            #pragma unroll
            for (int i = 0; i < 8; ++i) us[i] = 1.0f / (float)NN;
        } else {
            // ---- phase A: x_i = sum_j K~ v_j ; one v-fragment live at a time ----
            float xacc[8] = {0, 0, 0, 0, 0, 0, 0, 0};
            #define PA(HI, W, VOFF) { \
                fx4 v = *(const fx4*)(vv + cbase + (VOFF)); \
                dec4_dot(cb[0 + HI].W,  v, xacc[0]); \
                dec4_dot(cb[2 + HI].W,  v, xacc[1]); \
                dec4_dot(cb[4 + HI].W,  v, xacc[2]); \
                dec4_dot(cb[6 + HI].W,  v, xacc[3]); \
                dec4_dot(cb[8 + HI].W,  v, xacc[4]); \
                dec4_dot(cb[10 + HI].W, v, xacc[5]); \
                dec4_dot(cb[12 + HI].W, v, xacc[6]); \
                dec4_dot(cb[14 + HI].W, v, xacc[7]); }
            PA(0, x, 0)    PA(0, y, 4)    PA(0, z, 8)    PA(0, w, 12)
            PA(1, x, 1024) PA(1, y, 1028) PA(1, z, 1032) PA(1, w, 1036)
            #undef PA
            #pragma unroll
            for (int i = 0; i < 8; ++i) {
                float a = xacc[i];
                #pragma unroll
                for (int o = 32; o; o >>= 1) a += __shfl_xor(a, o);
                if (l == 0) xr[w][i] = a;
            }
            __syncthreads();
            if (t < 8) us_sh[t] = (1.0f / (float)NN) / (xr[0][t] + xr[1][t] + xr[2][t] + xr[3][t]);
            __syncthreads();
            #pragma unroll
            for (int i = 0; i < 8; ++i) us[i] = us_sh[i];
        }

        // ---- phase B: y_part[blk][cols] = sum_i u_i K~ ; one ya-pair live at a time ----
        {
            unsigned short* yp = y_part + (size_t)blk * NN + cbase;
            #define PB(HI, W0, W1, COFF) { \
                fx4 ya0 = {0, 0, 0, 0}; fx4 ya1 = {0, 0, 0, 0}; \
                dec4_axpy(cb[0 + HI].W0,  us[0], ya0); dec4_axpy(cb[0 + HI].W1,  us[0], ya1); \
                dec4_axpy(cb[2 + HI].W0,  us[1], ya0); dec4_axpy(cb[2 + HI].W1,  us[1], ya1); \
                dec4_axpy(cb[4 + HI].W0,  us[2], ya0); dec4_axpy(cb[4 + HI].W1,  us[2], ya1); \
                dec4_axpy(cb[6 + HI].W0,  us[3], ya0); dec4_axpy(cb[6 + HI].W1,  us[3], ya1); \
                dec4_axpy(cb[8 + HI].W0,  us[4], ya0); dec4_axpy(cb[8 + HI].W1,  us[4], ya1); \
                dec4_axpy(cb[10 + HI].W0, us[5], ya0); dec4_axpy(cb[10 + HI].W1, us[5], ya1); \
                dec4_axpy(cb[12 + HI].W0, us[6], ya0); dec4_axpy(cb[12 + HI].W1, us[6], ya1); \
                dec4_axpy(cb[14 + HI].W0, us[7], ya0); dec4_axpy(cb[14 + HI].W1, us[7], ya1); \
                ushort8 o; \
                o[0] = f2bf(ya0[0]); o[1] = f2bf(ya0[1]); o[2] = f2bf(ya0[2]); o[3] = f2bf(ya0[3]); \
                o[4] = f2bf(ya1[0]); o[5] = f2bf(ya1[1]); o[6] = f2bf(ya1[2]); o[7] = f2bf(ya1[3]); \
                *(ushort8*)(yp + (COFF)) = o; }
            PB(0, x, y, 0) PB(0, z, w, 8) PB(1, x, y, 1024) PB(1, z, w, 1032)
            #undef PB
        }

        __threadfence();   // release y_part (belt & suspenders around grid.sync)
        grid.sync();
        __threadfence();   // acquire before cross-block y_part reads

        // ---- reduce: v[col] = (1/N) / sum_c y_part[c][col]; block owns 8 cols ----
        {
            int col = blk * 8 + (t & 7);
            int seg = t >> 3;   // 0..31
            float s = 0.0f;
            #pragma unroll 4
            for (int c = seg * 32; c < seg * 32 + 32; ++c)
                s += bf2f(y_part[(size_t)c * NN + col]);
            red[t & 7][seg] = s;
            __syncthreads();
            if (t < 8) {
                float y = 0.0f;
                #pragma unroll
                for (int k = 0; k < 32; ++k) y += red[t][k];
                vv[blk * 8 + t] = (1.0f / (float)NN) / y;
            }
        }

        __threadfence();   // release vv
        grid.sync();
        __threadfence();   // acquire before cross-block vv reads
    }
}

// ---------------- loss pass: A_i = sum K~ v, B_i = sum ln(K~) K~ v -> tt = B/A ----------------
__global__ __launch_bounds__(256) void loss_k(const unsigned char* __restrict__ Kb,
                                              const float* __restrict__ vv,
                                              float* __restrict__ tt) {
    __shared__ float xrA[4][16];
    __shared__ float xrB[4][16];
    int t = threadIdx.x;
    int w = t >> 6, l = t & 63;
    size_t r0 = (size_t)blockIdx.x * 16;
    int cbase = w * 2048 + l * 16;
    fx4 vr[8];
    #pragma unroll
    for (int it = 0; it < 2; ++it)
        #pragma unroll
        for (int q = 0; q < 4; ++q)
            vr[it * 4 + q] = *(const fx4*)(vv + cbase + it * 1024 + q * 4);

    #pragma unroll
    for (int i = 0; i < 16; ++i) {
        float accA = 0.0f, accB = 0.0f;
        uint4 cbA = *(const uint4*)(Kb + (r0 + i) * NN + cbase);
        uint4 cbB = *(const uint4*)(Kb + (r0 + i) * NN + cbase + 1024);
        dec4_loss(cbA.x, vr[0], accA, accB);
        dec4_loss(cbA.y, vr[1], accA, accB);
        dec4_loss(cbA.z, vr[2], accA, accB);
        dec4_loss(cbA.w, vr[3], accA, accB);
        dec4_loss(cbB.x, vr[4], accA, accB);
        dec4_loss(cbB.y, vr[5], accA, accB);
        dec4_loss(cbB.z, vr[6], accA, accB);
        dec4_loss(cbB.w, vr[7], accA, accB);
        #pragma unroll
        for (int o = 32; o; o >>= 1) {
            accA += __shfl_xor(accA, o);
            accB += __shfl_xor(accB, o);
        }
        if (l == 0) { xrA[w][i] = accA; xrB[w][i] = accB; }
    }
    __syncthreads();
    if (t < 16) {
        float A = xrA[0][t] + xrA[1][t] + xrA[2][t] + xrA[3][t];
        float B = xrB[0][t] + xrB[1][t] + xrB[2][t] + xrB[3][t];
        tt[r0 + t] = B / A;
    }
}

// ---------------- out = (-reg/N) * sum_i tt_i ----------------
__global__ __launch_bounds__(256) void final_loss_k(const float* __restrict__ tt,
                                                    const float* __restrict__ regbuf,
                                                    float* __restrict__ out) {
    int t = threadIdx.x;
    float s = 0.0f;
    for (int i = t; i < NN; i += 256)
        s += tt[i];
    #pragma unroll
    for (int o = 32; o; o >>= 1) s += __shfl_xor(s, o);
    __shared__ float wsum[4];
    if ((t & 63) == 0) wsum[t >> 6] = s;
    __syncthreads();
    if (t == 0)
        out[0] = -regbuf[0] * (wsum[0] + wsum[1] + wsum[2] + wsum[3]) / (float)NN;
}

extern "C" void kernel_launch(void* const* d_in, const int* in_sizes, int n_in,
                              void* d_out, int out_size, void* d_ws, size_t ws_size,
                              hipStream_t stream) {
    const float* XP = (const float*)d_in[0];
    const float* XQ = (const float*)d_in[1];
    float* out = (float*)d_out;

    // workspace layout (~82.5 MiB)
    char* p = (char*)d_ws;
    unsigned char* Kb = (unsigned char*)p;     p += (size_t)NN * NN;          // 64 MiB
    unsigned short* y_part = (unsigned short*)p; p += (size_t)1024 * NN * 2;  // 16 MiB
    unsigned short* XPb = (unsigned short*)p;  p += (size_t)NN * DD * 2;      // 1 MiB
    unsigned short* XQb = (unsigned short*)p;  p += (size_t)NN * DD * 2;      // 1 MiB
    float* pn = (float*)p;                     p += NN * 4;
    float* qn = (float*)p;                     p += NN * 4;
    float* vv = (float*)p;                     p += NN * 4;
    float* tt = (float*)p;                     p += NN * 4;
    float* bm = (float*)p;                     p += 4096 * 4;
    float* regbuf = (float*)p;

    prep_k<<<4096, 256, 0, stream>>>(XP, XQ, XPb, XQb, pn, qn);
    gemm_max_k<<<dim3(64, 64), 256, 0, stream>>>(XPb, XQb, pn, qn, bm);
    max_red_k<<<1, 256, 0, stream>>>(bm, regbuf);
    gemm_K_k<<<dim3(64, 64), 256, 0, stream>>>(XPb, XQb, pn, qn, regbuf, Kb);

    // --- cooperative loop, gated by a deterministic occupancy precheck ---
    bool coop_ok = false;
    {
        int dev = 0;
        if (hipGetDevice(&dev) == hipSuccess) {
            int cuCount = 0, maxBlk = 0;
            if (hipDeviceGetAttribute(&cuCount, hipDeviceAttributeMultiprocessorCount, dev) == hipSuccess &&
                hipOccupancyMaxActiveBlocksPerMultiprocessor(&maxBlk, (const void*)sink_coop_k, 256, 0) == hipSuccess) {
                if ((long)maxBlk * (long)cuCount >= 1024L) coop_ok = true;
            }
        }
    }
    if (coop_ok) {
        void* kargs[3] = {(void*)&Kb, (void*)&vv, (void*)&y_part};
        hipError_t e = hipLaunchCooperativeKernel((const void*)sink_coop_k, dim3(1024), dim3(256),
                                                  kargs, 0, stream);
        if (e != hipSuccess) coop_ok = false;
    }
    if (!coop_ok) {
        // fallback: proven round-8 loop
        for (int it = 0; it < NITER; ++it) {
            sink_k<<<1024, 256, 0, stream>>>(Kb, vv, y_part, it);
            reduce_v_k<<<128, 256, 0, stream>>>(y_part, vv);
        }
    }

    loss_k<<<512, 256, 0, stream>>>(Kb, vv, tt);
    final_loss_k<<<1, 256, 0, stream>>>(tt, regbuf, out);
}